// Round 4
// baseline (2607.912 us; speedup 1.0000x reference)
//
#include <hip/hip_runtime.h>

#define NPIECE 499
#define SEQN 500

typedef __attribute__((ext_vector_type(8))) short bf16x8;
typedef __attribute__((ext_vector_type(4))) float f32x4;

__device__ inline short f2bf(float x) {
    union { float f; unsigned u; } v; v.f = x;
    unsigned r = v.u + 0x7FFFu + ((v.u >> 16) & 1u);   // RNE fp32->bf16
    return (short)(r >> 16);
}

__device__ inline unsigned cvt_pk(float lo, float hi) {  // D.lo=bf16(lo), D.hi=bf16(hi)
    unsigned r;
    asm("v_cvt_pk_bf16_f32 %0, %1, %2" : "=v"(r) : "v"(lo), "v"(hi));
    return r;
}

__device__ inline float fast_tanh(float x) {
    float e = __expf(2.0f * x);
    return 1.0f - 2.0f * __builtin_amdgcn_rcpf(e + 1.0f);
}

// One block = 16 samples, 8 waves, 32 blocks. One barrier per MLP eval:
// every wave computes full layer-1 redundantly; the MFMA k-permutation is
// chosen so L1's D-fragments are directly the L2 B-operand slots (no LDS h).
__global__ void __launch_bounds__(512, 2)
cde_kernel(const float* __restrict__ times,
           const float* __restrict__ ca,  const float* __restrict__ cb,
           const float* __restrict__ c2c, const float* __restrict__ c3d,
           const float* __restrict__ initW, const float* __restrict__ initb,
           const float* __restrict__ W1,  const float* __restrict__ b1,
           const float* __restrict__ W2,  const float* __restrict__ b2,
           const float* __restrict__ linW, const float* __restrict__ linb,
           float* __restrict__ out)
{
    const int tid  = threadIdx.x;
    const int lane = tid & 63;
    const int wv   = tid >> 6;      // wave 0..7
    const int g    = lane >> 4;     // 0..3
    const int col  = lane & 15;     // sample (B/D col), weight row (A)
    const int g0   = g & 1;
    const int hi   = lane >> 5;     // == g>>1
    const int s0   = blockIdx.x * 16;

    __shared__ __align__(16) float tl[SEQN];
    __shared__ __align__(16) short zflat[2][8][16][8];  // stage-parity dbuf
    __shared__ __align__(16) float dxl[2][3][2][16][4]; // [par][slot][g0][sm][r]
    __shared__ __align__(16) float zinit[64][16];
    __shared__ __align__(16) float pred[8][16];

    for (int j = tid; j < SEQN; j += 512) tl[j] = times[j];

    // ---- A2 fragments: k-perm q(c,g,e) = 32c + 16(e>>2) + 4g + (e&3) -------
    bf16x8 a2[4][4];
    f32x4  b2f[4];
#pragma unroll
    for (int tt = 0; tt < 4; ++tt) {
        const int o = 16 * (4 * wv + tt) + col;
#pragma unroll
        for (int c = 0; c < 4; ++c) {
            bf16x8 f;
#pragma unroll
            for (int e = 0; e < 8; ++e) {
                const int q = 32 * c + 16 * (e >> 2) + 4 * g + (e & 3);
                f[e] = f2bf(W2[q * 512 + o]);
            }
            a2[tt][c] = f;
        }
#pragma unroll
        for (int r = 0; r < 4; ++r)
            b2f[tt][r] = b2[16 * (4 * wv + tt) + 4 * g + r];
    }
    // ---- A1 fragments (full L1): k-perm p(c,g,e) = 32c + 8g + 2(e&3)+(e>>2)
    bf16x8 a1[8][2];
    f32x4  b1f[8];
#pragma unroll
    for (int t = 0; t < 8; ++t) {
#pragma unroll
        for (int c = 0; c < 2; ++c) {
            bf16x8 f;
#pragma unroll
            for (int e = 0; e < 8; ++e) {
                const int p = 32 * c + 8 * g + 2 * (e & 3) + (e >> 2);
                f[e] = f2bf(W1[p * 128 + 16 * t + col]);
            }
            a1[t][c] = f;
        }
#pragma unroll
        for (int r = 0; r < 4; ++r) b1f[t][r] = b1[16 * t + 4 * g + r];
    }

    __syncthreads();   // tl ready

    // ---- z0 = X(t0) @ init_W + init_b; store with pi(2tt+hi)=4hi+tt --------
#pragma unroll
    for (int v = 0; v < 2; ++v) {
        const int idx = tid * 2 + v, hid = idx >> 4, sm = idx & 15;
        float z = initb[hid];
#pragma unroll
        for (int c = 0; c < 8; ++c)
            z += ca[((size_t)(s0 + sm)) * (NPIECE * 8) + c] * initW[c * 64 + hid];
        zinit[hid][sm] = z;
        zflat[0][hid >> 3][sm][4 * (hid & 1) + ((hid & 7) >> 1)] = f2bf(z);
    }
    // ---- dx for step 0 -------------------------------------------------------
    const int pslot = tid >> 7, prr = tid & 127, psm = prr >> 3, pch = prr & 7;
    const size_t prow = ((size_t)(s0 + psm)) * (NPIECE * 8);
    if (tid < 384) {
        float t0n = tl[0], t1n = tl[1], hn = t1n - t0n; int p; float fr;
        if (pslot == 0)      { p = 0; fr = 0.0f; }
        else if (pslot == 1) { p = 0; fr = (t0n + 0.5f * hn) - t0n; }
        else { float t3 = t0n + hn;
               if (t3 > t1n) { p = 1; fr = t3 - t1n; } else { p = 0; fr = t3 - t0n; } }
        const size_t off = prow + (size_t)p * 8 + pch;
        dxl[0][pslot][pch >> 2][psm][pch & 3] = cb[off] + (c2c[off] + c3d[off] * fr) * fr;
    }
    __syncthreads();

    // RK4 state: every lane tracks z[8wv+2tt+hi][col]; lanes with (lane&16)==0 write
    float zreg[4], zs[4];
#pragma unroll
    for (int tt = 0; tt < 4; ++tt) {
        zs[tt] = 0.f;
        zreg[tt] = zinit[8 * wv + 2 * tt + hi][col];
    }

    for (int i = 0; i < NPIECE; ++i) {
        const float hs = tl[i + 1] - tl[i];
        const int par = i & 1;

        // register-prefetch next step's spline coefficients
        float pb = 0.f, pc = 0.f, pd = 0.f, pfr = 0.f;
        const bool pf = (i + 1 < NPIECE) && (tid < 384);
        if (pf) {
            const int j = i + 1;
            float t0n = tl[j], t1n = tl[j + 1], hn = t1n - t0n; int p; float fr;
            if (pslot == 0)      { p = j - 1; fr = t0n - tl[j - 1]; }
            else if (pslot == 1) { p = j; fr = (t0n + 0.5f * hn) - t0n; }
            else { float t3 = t0n + hn;
                   if (j < NPIECE - 1 && t3 > t1n) { p = j + 1; fr = t3 - t1n; }
                   else                            { p = j;     fr = t3 - t0n; } }
            const size_t off = prow + (size_t)p * 8 + pch;
            pb = cb[off]; pc = c2c[off]; pd = c3d[off]; pfr = fr;
        }

        f32x4 ddr0, ddr1, ddr2;
#pragma unroll
        for (int st = 0; st < 4; ++st) {
            const int rb = st & 1, wb = rb ^ 1;
            __syncthreads();   // the ONLY barrier per eval

            if (st == 0) {     // prefetch all 3 dx slots for this step
                ddr0 = *(const f32x4*)&dxl[par][0][g0][col][0];
                ddr1 = *(const f32x4*)&dxl[par][1][g0][col][0];
                ddr2 = *(const f32x4*)&dxl[par][2][g0][col][0];
            }
            if (st == 3 && pf)
                dxl[par ^ 1][pslot][pch >> 2][psm][pch & 3] = pb + (pc + pd * pfr) * pfr;

            // ---- layer1 (full, redundant per wave): h = relu(z @ W1 + b1) ----
            bf16x8 bz0 = *(const bf16x8*)&zflat[rb][g][col][0];
            bf16x8 bz1 = *(const bf16x8*)&zflat[rb][4 + g][col][0];
            f32x4 ha[8];
#pragma unroll
            for (int t = 0; t < 8; ++t)
                ha[t] = __builtin_amdgcn_mfma_f32_16x16x32_bf16(a1[t][0], bz0, b1f[t], 0, 0, 0);
#pragma unroll
            for (int t = 0; t < 8; ++t)
                ha[t] = __builtin_amdgcn_mfma_f32_16x16x32_bf16(a1[t][1], bz1, ha[t], 0, 0, 0);

            // ---- relu + pack: D-frags ARE the L2 B-frags under the q-perm ----
            union { bf16x8 v; unsigned u[4]; } bh[4];
#pragma unroll
            for (int c = 0; c < 4; ++c) {
                bh[c].u[0] = cvt_pk(fmaxf(ha[2 * c][0], 0.f), fmaxf(ha[2 * c][1], 0.f));
                bh[c].u[1] = cvt_pk(fmaxf(ha[2 * c][2], 0.f), fmaxf(ha[2 * c][3], 0.f));
                bh[c].u[2] = cvt_pk(fmaxf(ha[2 * c + 1][0], 0.f), fmaxf(ha[2 * c + 1][1], 0.f));
                bh[c].u[3] = cvt_pk(fmaxf(ha[2 * c + 1][2], 0.f), fmaxf(ha[2 * c + 1][3], 0.f));
            }

            // ---- layer2: 4 tiles, v = h @ W2 (bias at tanh) ----
            f32x4 cc[4];
#pragma unroll
            for (int tt = 0; tt < 4; ++tt) cc[tt] = (f32x4){0.f, 0.f, 0.f, 0.f};
#pragma unroll
            for (int c = 0; c < 4; ++c)
#pragma unroll
                for (int tt = 0; tt < 4; ++tt)
                    cc[tt] = __builtin_amdgcn_mfma_f32_16x16x32_bf16(a2[tt][c], bh[c].v, cc[tt], 0, 0, 0);

            // ---- tanh + contraction ----
            f32x4 dd = (st == 0) ? ddr0 : ((st == 3) ? ddr2 : ddr1);
            float pt[4];
#pragma unroll
            for (int tt = 0; tt < 4; ++tt) {
                float sacc = 0.f;
#pragma unroll
                for (int r = 0; r < 4; ++r)
                    sacc += fast_tanh(cc[tt][r] + b2f[tt][r]) * dd[r];
                pt[tt] = sacc;
            }
#pragma unroll
            for (int tt = 0; tt < 4; ++tt)
                pt[tt] += __shfl_xor(pt[tt], 16);   // sum over g0

            // ---- RK4 update (all lanes track; g0==0 lanes write) ----
            float zw[4];
#pragma unroll
            for (int tt = 0; tt < 4; ++tt) {
                const float k = pt[tt];
                float zst;
                if (st == 0)      { zs[tt] = k;          zst = zreg[tt] + 0.5f * hs * k; }
                else if (st == 1) { zs[tt] += 2.f * k;   zst = zreg[tt] + 0.5f * hs * k; }
                else if (st == 2) { zs[tt] += 2.f * k;   zst = zreg[tt] + hs * k; }
                else              { zs[tt] += k;         zst = zreg[tt] + (hs / 6.f) * zs[tt];
                                    zreg[tt] = zst; }
                zw[tt] = zst;
            }
            if (!(lane & 16)) {
                int2 wdat;
                wdat.x = (int)cvt_pk(zw[0], zw[1]);
                wdat.y = (int)cvt_pk(zw[2], zw[3]);
                *(int2*)&zflat[wb][wv][col][4 * hi] = wdat;
            }
        }
    }

    // ---------------- readout: sigmoid(z @ lin_W + lin_b) --------------------
    float p = 0.f;
#pragma unroll
    for (int tt = 0; tt < 4; ++tt) p += zreg[tt] * linW[8 * wv + 2 * tt + hi];
    p += __shfl_xor(p, 32);
    if (lane < 16) pred[wv][col] = p;
    __syncthreads();
    if (tid < 16) {
        float a = linb[0];
#pragma unroll
        for (int w = 0; w < 8; ++w) a += pred[w][tid];
        out[s0 + tid] = 1.0f / (1.0f + __expf(-a));
    }
}

extern "C" void kernel_launch(void* const* d_in, const int* in_sizes, int n_in,
                              void* d_out, int out_size, void* d_ws, size_t ws_size,
                              hipStream_t stream) {
    (void)in_sizes; (void)n_in; (void)d_ws; (void)ws_size; (void)out_size;
    const float* times = (const float*)d_in[0];
    const float* ca    = (const float*)d_in[1];
    const float* cb    = (const float*)d_in[2];
    const float* c2c   = (const float*)d_in[3];
    const float* c3d   = (const float*)d_in[4];
    const float* initW = (const float*)d_in[5];
    const float* initb = (const float*)d_in[6];
    const float* W1    = (const float*)d_in[7];
    const float* b1    = (const float*)d_in[8];
    const float* W2    = (const float*)d_in[9];
    const float* b2    = (const float*)d_in[10];
    const float* linW  = (const float*)d_in[11];
    const float* linb  = (const float*)d_in[12];
    cde_kernel<<<32, 512, 0, stream>>>(times, ca, cb, c2c, c3d, initW, initb,
                                       W1, b1, W2, b2, linW, linb, (float*)d_out);
}

// Round 5
// 1866.294 us; speedup vs baseline: 1.3974x; 1.3974x over previous
//
#include <hip/hip_runtime.h>

#define NPIECE 499
#define SEQN 500

typedef __attribute__((ext_vector_type(8))) short bf16x8;
typedef __attribute__((ext_vector_type(4))) float f32x4;

__device__ inline short f2bf(float x) {
    union { float f; unsigned u; } v; v.f = x;
    unsigned r = v.u + 0x7FFFu + ((v.u >> 16) & 1u);   // RNE fp32->bf16
    return (short)(r >> 16);
}

__device__ inline unsigned cvt_pk(float lo, float hi) {  // D.lo=bf16(lo), D.hi=bf16(hi)
    unsigned r;
    asm("v_cvt_pk_bf16_f32 %0, %1, %2" : "=v"(r) : "v"(lo), "v"(hi));
    return r;
}

// slim tanh: 1 - 2*rcp(exp2(x*2log2e)+1)  (3 VALU + 2 trans)
__device__ inline float fast_tanh(float x) {
    float e = __builtin_amdgcn_exp2f(x * 2.8853900817779268f);
    float r = __builtin_amdgcn_rcpf(e + 1.0f);
    return fmaf(-2.0f, r, 1.0f);
}

__device__ inline float xor16(float x) {
    return __int_as_float(__builtin_amdgcn_ds_swizzle(__float_as_int(x), 0x401f));
}

// One block = 16 samples (full MFMA N), 8 waves. 32 blocks.
__global__ void __launch_bounds__(512, 2)
cde_kernel(const float* __restrict__ times,
           const float* __restrict__ ca,  const float* __restrict__ cb,
           const float* __restrict__ c2c, const float* __restrict__ c3d,
           const float* __restrict__ initW, const float* __restrict__ initb,
           const float* __restrict__ W1,  const float* __restrict__ b1,
           const float* __restrict__ W2,  const float* __restrict__ b2,
           const float* __restrict__ linW, const float* __restrict__ linb,
           float* __restrict__ out)
{
    const int tid  = threadIdx.x;
    const int lane = tid & 63;
    const int wv   = tid >> 6;      // wave 0..7
    const int g    = lane >> 4;     // 0..3
    const int col  = lane & 15;     // sample (B/D col), weight row (A)
    const int g0   = g & 1, g1 = g >> 1;
    const int hi   = lane >> 5;
    const int s0   = blockIdx.x * 16;

    // zigzag bf16 activation layout: elem (k, sample) at [(k>>3)][sample][k&7]
    __shared__ __align__(16) float tl[SEQN];
    __shared__ __align__(16) short zflat[8][16][8];     // z  (K=64)
    __shared__ __align__(16) short hflat[16][16][8];    // h  (K=128)
    __shared__ __align__(16) float dxl[2][3][2][16][4]; // [par][slot][g0][sample][r]
    __shared__ __align__(16) float zinit[64][16];
    __shared__ __align__(16) float pred[8][16];

    for (int j = tid; j < SEQN; j += 512) tl[j] = times[j];

    // ---------------- weight fragments (bf16, registers) ---------------------
    // layer2: wave owns 4 output tiles (o = 16*(4wv+tt) + col), K=128 -> 4 chunks
    bf16x8 a2[4][4];
    f32x4  b2f[4];
#pragma unroll
    for (int tt = 0; tt < 4; ++tt) {
        const int o = 16 * (4 * wv + tt) + col;
#pragma unroll
        for (int kk = 0; kk < 4; ++kk) {
            bf16x8 f;
#pragma unroll
            for (int e = 0; e < 8; ++e)
                f[e] = f2bf(W2[(32 * kk + 8 * g + e) * 512 + o]);
            a2[tt][kk] = f;
        }
#pragma unroll
        for (int r = 0; r < 4; ++r)
            b2f[tt][r] = b2[16 * (4 * wv + tt) + 4 * g + r];
    }
    // layer1: wave owns 1 output tile (h = 16wv + col), K=64 -> 2 chunks
    bf16x8 a1[2];
    f32x4  b1f;
    {
        const int o = 16 * wv + col;
#pragma unroll
        for (int kk = 0; kk < 2; ++kk) {
            bf16x8 f;
#pragma unroll
            for (int e = 0; e < 8; ++e)
                f[e] = f2bf(W1[(32 * kk + 8 * g + e) * 128 + o]);
            a1[kk] = f;
        }
#pragma unroll
        for (int r = 0; r < 4; ++r) b1f[r] = b1[16 * wv + 4 * g + r];
    }

    __syncthreads();   // tl ready

    // ---------------- z0 = X(t0) @ init_W + init_b ---------------------------
#pragma unroll
    for (int v = 0; v < 2; ++v) {
        const int idx = tid * 2 + v, hid = idx >> 4, sm = idx & 15;
        float z = initb[hid];
#pragma unroll
        for (int c = 0; c < 8; ++c)
            z += ca[((size_t)(s0 + sm)) * (NPIECE * 8) + c] * initW[c * 64 + hid];
        zinit[hid][sm] = z;
        zflat[hid >> 3][sm][hid & 7] = f2bf(z);
    }
    // ---------------- dx for step 0 ------------------------------------------
    const int pslot = tid >> 7, prr = tid & 127, psm = prr >> 3, pch = prr & 7;
    const size_t prow = ((size_t)(s0 + psm)) * (NPIECE * 8);
    if (tid < 384) {
        float t0n = tl[0], t1n = tl[1], hn = t1n - t0n; int p; float fr;
        if (pslot == 0)      { p = 0; fr = 0.0f; }
        else if (pslot == 1) { p = 0; fr = (t0n + 0.5f * hn) - t0n; }
        else { float t3 = t0n + hn;
               if (t3 > t1n) { p = 1; fr = t3 - t1n; } else { p = 0; fr = t3 - t0n; } }
        const size_t off = prow + (size_t)p * 8 + pch;
        dxl[0][pslot][pch >> 2][psm][pch & 3] = cb[off] + (c2c[off] + c3d[off] * fr) * fr;
    }
    __syncthreads();

    // RK4 state: owner lanes (lane&31)<16 hold z[8wv+2tt+hi][col], tt=0..3
    const bool owner = ((lane & 31) < 16);
    float zreg[4], zs[4];
#pragma unroll
    for (int tt = 0; tt < 4; ++tt) {
        zs[tt] = 0.f;
        zreg[tt] = zinit[8 * wv + 2 * tt + hi][col];
    }

    for (int i = 0; i < NPIECE; ++i) {
        const float hs = tl[i + 1] - tl[i];
        const float hs_half = 0.5f * hs, hs_sixth = hs * (1.0f / 6.0f);
        const int par = i & 1;

        // register-prefetch next step's spline coefficients
        float pb = 0.f, pc = 0.f, pd = 0.f, pfr = 0.f;
        const bool pf = (i + 1 < NPIECE) && (tid < 384);
        if (pf) {
            const int j = i + 1;
            float t0n = tl[j], t1n = tl[j + 1], hn = t1n - t0n; int p; float fr;
            if (pslot == 0)      { p = j - 1; fr = t0n - tl[j - 1]; }
            else if (pslot == 1) { p = j; fr = (t0n + 0.5f * hn) - t0n; }
            else { float t3 = t0n + hn;
                   if (j < NPIECE - 1 && t3 > t1n) { p = j + 1; fr = t3 - t1n; }
                   else                            { p = j;     fr = t3 - t0n; } }
            const size_t off = prow + (size_t)p * 8 + pch;
            pb = cb[off]; pc = c2c[off]; pd = c3d[off]; pfr = fr;
        }

#pragma unroll
        for (int st = 0; st < 4; ++st) {
            const int dsel = (st == 0) ? 0 : ((st == 3) ? 2 : 1);
            __syncthreads();   // barrier A: zflat (and dxl[par]) ready

            if (st == 3 && pf)
                dxl[par ^ 1][pslot][pch >> 2][psm][pch & 3] = pb + (pc + pd * pfr) * pfr;

            // ---- layer1: h-tile = relu(z @ W1 + b1) (bias via C-init) ----
            bf16x8 bz0 = *(const bf16x8*)&zflat[g][col][0];
            bf16x8 bz1 = *(const bf16x8*)&zflat[4 + g][col][0];
            f32x4 ha;
            ha = __builtin_amdgcn_mfma_f32_16x16x32_bf16(a1[0], bz0, b1f, 0, 0, 0);
            ha = __builtin_amdgcn_mfma_f32_16x16x32_bf16(a1[1], bz1, ha, 0, 0, 0);
            // relu + pack via cvt_pk, one 8B store per lane
            int2 hw;
            hw.x = (int)cvt_pk(fmaxf(ha[0], 0.f), fmaxf(ha[1], 0.f));
            hw.y = (int)cvt_pk(fmaxf(ha[2], 0.f), fmaxf(ha[3], 0.f));
            *(int2*)&hflat[2 * wv + g1][col][4 * g0] = hw;
            __syncthreads();   // barrier B: hflat ready

            // ---- layer2: 4 tiles, v = h @ W2 + b2 (bias via C-init) ----
            bf16x8 bh[4];
#pragma unroll
            for (int c = 0; c < 4; ++c)
                bh[c] = *(const bf16x8*)&hflat[4 * c + g][col][0];
            f32x4 cc[4];
#pragma unroll
            for (int tt = 0; tt < 4; ++tt)
                cc[tt] = __builtin_amdgcn_mfma_f32_16x16x32_bf16(a2[tt][0], bh[0], b2f[tt], 0, 0, 0);
#pragma unroll
            for (int kk = 1; kk < 4; ++kk)
#pragma unroll
                for (int tt = 0; tt < 4; ++tt)
                    cc[tt] = __builtin_amdgcn_mfma_f32_16x16x32_bf16(a2[tt][kk], bh[kk], cc[tt], 0, 0, 0);

            // ---- in-register tanh + contraction ----
            f32x4 dd = *(const f32x4*)&dxl[par][dsel][g0][col][0];
            float pt[4];
#pragma unroll
            for (int tt = 0; tt < 4; ++tt) {
                float sacc = 0.f;
#pragma unroll
                for (int r = 0; r < 4; ++r)
                    sacc = fmaf(fast_tanh(cc[tt][r]), dd[r], sacc);
                pt[tt] = sacc;
            }
#pragma unroll
            for (int tt = 0; tt < 4; ++tt)
                pt[tt] += xor16(pt[tt]);   // combine g0=0/1 -> full sum over i

            // ---- RK4 update (owner lanes), write next-stage z ----
            if (owner) {
#pragma unroll
                for (int tt = 0; tt < 4; ++tt) {
                    const float k = pt[tt];
                    float zst;
                    if (st == 0)      { zs[tt] = k;          zst = fmaf(hs_half, k, zreg[tt]); }
                    else if (st == 1) { zs[tt] = fmaf(2.f, k, zs[tt]); zst = fmaf(hs_half, k, zreg[tt]); }
                    else if (st == 2) { zs[tt] = fmaf(2.f, k, zs[tt]); zst = fmaf(hs, k, zreg[tt]); }
                    else              { zs[tt] += k;         zst = fmaf(hs_sixth, zs[tt], zreg[tt]);
                                        zreg[tt] = zst; }
                    zflat[wv][col][2 * tt + hi] = f2bf(zst);
                }
            }
        }
    }

    // ---------------- readout: sigmoid(z @ lin_W + lin_b) --------------------
    float p = 0.f;
#pragma unroll
    for (int tt = 0; tt < 4; ++tt) p += zreg[tt] * linW[8 * wv + 2 * tt + hi];
    p += __shfl_xor(p, 32);
    if (lane < 16) pred[wv][col] = p;
    __syncthreads();
    if (tid < 16) {
        float a = linb[0];
#pragma unroll
        for (int w = 0; w < 8; ++w) a += pred[w][tid];
        out[s0 + tid] = 1.0f / (1.0f + __expf(-a));
    }
}

extern "C" void kernel_launch(void* const* d_in, const int* in_sizes, int n_in,
                              void* d_out, int out_size, void* d_ws, size_t ws_size,
                              hipStream_t stream) {
    (void)in_sizes; (void)n_in; (void)d_ws; (void)ws_size; (void)out_size;
    const float* times = (const float*)d_in[0];
    const float* ca    = (const float*)d_in[1];
    const float* cb    = (const float*)d_in[2];
    const float* c2c   = (const float*)d_in[3];
    const float* c3d   = (const float*)d_in[4];
    const float* initW = (const float*)d_in[5];
    const float* initb = (const float*)d_in[6];
    const float* W1    = (const float*)d_in[7];
    const float* b1    = (const float*)d_in[8];
    const float* W2    = (const float*)d_in[9];
    const float* b2    = (const float*)d_in[10];
    const float* linW  = (const float*)d_in[11];
    const float* linb  = (const float*)d_in[12];
    cde_kernel<<<32, 512, 0, stream>>>(times, ca, cb, c2c, c3d, initW, initb,
                                       W1, b1, W2, b2, linW, linb, (float*)d_out);
}